// Round 1
// baseline (1003.804 us; speedup 1.0000x reference)
//
#include <hip/hip_runtime.h>
#include <math.h>

// Problem constants (B=1)
#define LTOK 4096   // H*W tokens
#define CCH  96     // C
#define DIN_ 192
#define KDIR 4
#define NST  16
#define RRK  6
#define KD_  768    // K*DIN

// ---------------- workspace layout (floats) ----------------
#define O_XN     0
#define O_XLN    393216
#define O_XZ     786432      // 4096*384
#define O_XCONV  2359296     // 192*4096
#define O_XCONVT 3145728
#define O_DELTA  3932160     // 768*4096  (scan-order per kd)
#define O_BM     7077888     // 4*4096*16 (k,l,n)
#define O_CM     7340032
#define O_PB     7602176     // 768*64*16
#define O_QB     8388608
#define O_HS     9175040
#define O_YS     9961472     // 4*4096*192 (k, scanpos, d)
#define O_XCUR   13107200
// total 13500416 floats = ~51.5 MB

__device__ __forceinline__ float siluf(float x) { return x / (1.f + __expf(-x)); }

// K1: double layernorm per token (C=96). 4 tokens per 256-block, one wave each.
__global__ void ln2_kernel(const float* __restrict__ x, float* __restrict__ xn, float* __restrict__ xln,
                           const float* __restrict__ g1, const float* __restrict__ b1,
                           const float* __restrict__ g2, const float* __restrict__ b2) {
  int tid = threadIdx.x, wid = tid >> 6, lane = tid & 63;
  int l = blockIdx.x * 4 + wid;
  const float* xr = x + l * CCH;
  float v0 = xr[lane];
  float v1 = (lane < 32) ? xr[64 + lane] : 0.f;
  float s = v0 + v1, ss = v0 * v0 + v1 * v1;
  for (int off = 32; off > 0; off >>= 1) { s += __shfl_xor(s, off); ss += __shfl_xor(ss, off); }
  float m = s * (1.f / 96.f);
  float rs = rsqrtf(ss * (1.f / 96.f) - m * m + 1e-5f);
  float n0 = (v0 - m) * rs * g1[lane] + b1[lane];
  float n1 = (lane < 32) ? (v1 - m) * rs * g1[64 + lane] + b1[64 + lane] : 0.f;
  xn[l * CCH + lane] = n0;
  if (lane < 32) xn[l * CCH + 64 + lane] = n1;
  float s2 = n0 + n1, ss2 = n0 * n0 + n1 * n1;
  for (int off = 32; off > 0; off >>= 1) { s2 += __shfl_xor(s2, off); ss2 += __shfl_xor(ss2, off); }
  float m2 = s2 * (1.f / 96.f);
  float rs2 = rsqrtf(ss2 * (1.f / 96.f) - m2 * m2 + 1e-5f);
  xln[l * CCH + lane] = (n0 - m2) * rs2 * g2[lane] + b2[lane];
  if (lane < 32) xln[l * CCH + 64 + lane] = (n1 - m2) * rs2 * g2[64 + lane] + b2[64 + lane];
}

// K2: in_proj  xz[l, 0..383] = xln[l,:] @ W^T.  One token per 128-thread block.
__global__ void inproj_kernel(const float* __restrict__ xln, const float* __restrict__ w,
                              float* __restrict__ xz) {
  int l = blockIdx.x;
  __shared__ float xr[96];
  int tid = threadIdx.x;
  if (tid < 96) xr[tid] = xln[l * CCH + tid];
  __syncthreads();
  for (int j = tid; j < 384; j += 128) {
    const float* wr = w + j * 96;
    float acc = 0.f;
#pragma unroll 8
    for (int c = 0; c < 96; ++c) acc += xr[c] * wr[c];
    xz[l * 384 + j] = acc;
  }
}

// K3: depthwise 3x3 conv + bias + silu.  Output channel-major xconv[d][l].
// block: h row x 32-d tile
__global__ void dwconv_kernel(const float* __restrict__ xz, const float* __restrict__ cw,
                              const float* __restrict__ cb, float* __restrict__ xconv) {
  int h = blockIdx.x;
  int d0 = blockIdx.y * 32;
  __shared__ float xs[3][64][33];
  int tid = threadIdx.x;
  for (int idx = tid; idx < 3 * 64 * 32; idx += 256) {
    int dd = idx & 31;
    int w = (idx >> 5) & 63;
    int r = idx >> 11;
    int hh = h + r - 1;
    float v = 0.f;
    if (hh >= 0 && hh < 64) v = xz[(hh * 64 + w) * 384 + d0 + dd];
    xs[r][w][dd] = v;
  }
  __syncthreads();
  int w = tid & 63;
  int dsub = tid >> 6;
  for (int dd = dsub; dd < 32; dd += 4) {
    int d = d0 + dd;
    float acc = cb[d];
    const float* wgt = cw + d * 9;
#pragma unroll
    for (int r = 0; r < 3; ++r)
#pragma unroll
      for (int c = 0; c < 3; ++c) {
        int ww = w + c - 1;
        if (ww >= 0 && ww < 64) acc += xs[r][ww][dd] * wgt[r * 3 + c];
      }
    xconv[d * LTOK + h * 64 + w] = siluf(acc);
  }
}

// K3T: per-channel 64x64 transpose. xconvT[d][w*64+h] = xconv[d][h*64+w]
__global__ void transpose64_kernel(const float* __restrict__ in, float* __restrict__ out) {
  int d = blockIdx.x;
  __shared__ float t[64][65];
  const float* src = in + d * LTOK;
  float* dst = out + d * LTOK;
  int tid = threadIdx.x;
  for (int idx = tid; idx < 4096; idx += 256) {
    int w = idx & 63, h = idx >> 6;
    t[h][w] = src[idx];
  }
  __syncthreads();
  for (int idx = tid; idx < 4096; idx += 256) {
    int hh = idx & 63, ww = idx >> 6;
    dst[idx] = t[hh][ww];
  }
}

// K4: x_proj + dt proj + softplus.  One block per (direction k, 64-pos chunk).
__global__ void projdelta_kernel(const float* __restrict__ xconv, const float* __restrict__ xconvT,
                                 const float* __restrict__ xpw, const float* __restrict__ dtw,
                                 const float* __restrict__ dtb, float* __restrict__ delta,
                                 float* __restrict__ Bm, float* __restrict__ Cm) {
  int chunk = blockIdx.x;
  int k = blockIdx.y;
  int l0 = chunk * 64;
  __shared__ float xsm[192 * 64];
  __shared__ float xdm[38 * 64];
  int tid = threadIdx.x;
  const float* ub = ((k & 1) ? xconvT : xconv);
  bool rev = (k >= 2);
  for (int idx = tid; idx < 192 * 64; idx += 256) {
    int i = idx & 63, d = idx >> 6;
    int l = l0 + i;
    xsm[idx] = ub[d * LTOK + (rev ? 4095 - l : l)];
  }
  __syncthreads();
  for (int o = tid; o < 38 * 64; o += 256) {
    int i = o & 63, c = o >> 6;
    const float* wr = xpw + (k * 38 + c) * 192;
    float acc = 0.f;
#pragma unroll 8
    for (int d = 0; d < 192; ++d) acc += wr[d] * xsm[d * 64 + i];
    xdm[o] = acc;
    if (c >= 6) {
      int l = l0 + i;
      if (c < 22) Bm[(k * LTOK + l) * NST + (c - 6)] = acc;
      else        Cm[(k * LTOK + l) * NST + (c - 22)] = acc;
    }
  }
  __syncthreads();
  for (int o = tid; o < 192 * 64; o += 256) {
    int i = o & 63, d = o >> 6;
    float acc = dtb[k * 192 + d];
    const float* wr = dtw + (k * 192 + d) * 6;
#pragma unroll
    for (int r = 0; r < 6; ++r) acc += xdm[r * 64 + i] * wr[r];
    float sp = (acc > 20.f) ? acc : log1pf(__expf(acc));
    delta[(k * 192 + d) * LTOK + l0 + i] = sp;
  }
}

// Scan pass 1: per (kd, chunk, n): P = prod a, q = local scan end state
__global__ void scan_pass1(const float* __restrict__ delta, const float* __restrict__ Bm,
                           const float* __restrict__ xconv, const float* __restrict__ xconvT,
                           const float* __restrict__ A_logs, float* __restrict__ Pb,
                           float* __restrict__ qb) {
  int g = blockIdx.x * 256 + threadIdx.x;
  int n = g & 15;
  int chunk = (g >> 4) & 63;
  int kd = g >> 10;
  int k = kd / 192, d = kd - k * 192;
  const float* ub = ((k & 1) ? xconvT : xconv) + d * LTOK;
  bool rev = (k >= 2);
  float A = -__expf(A_logs[kd * NST + n]);
  const float* dp = delta + kd * LTOK;
  const float* bp = Bm + k * LTOK * NST + n;
  float P = 1.f, q = 0.f;
  int l0 = chunk * 64;
  for (int t = 0; t < 64; ++t) {
    int l = l0 + t;
    float dlt = dp[l];
    float u = ub[rev ? 4095 - l : l];
    float a = __expf(dlt * A);
    float b = dlt * bp[l * NST] * u;
    q = a * q + b;
    P *= a;
  }
  int o = (kd * 64 + chunk) * NST + n;
  Pb[o] = P;
  qb[o] = q;
}

// Scan pass 2: inter-chunk scan (64 steps), emits per-chunk initial state
__global__ void scan_pass2(const float* __restrict__ Pb, const float* __restrict__ qb,
                           float* __restrict__ hs) {
  int g = blockIdx.x * 256 + threadIdx.x;  // 12288 threads
  int n = g & 15, kd = g >> 4;
  float h = 0.f;
  for (int c = 0; c < 64; ++c) {
    int o = (kd * 64 + c) * NST + n;
    hs[o] = h;
    h = Pb[o] * h + qb[o];
  }
}

// Scan pass 3: replay chunk with correct h0, emit y (16-lane reduce over n)
__global__ void scan_pass3(const float* __restrict__ delta, const float* __restrict__ Bm,
                           const float* __restrict__ Cm, const float* __restrict__ xconv,
                           const float* __restrict__ xconvT, const float* __restrict__ A_logs,
                           const float* __restrict__ Ds, const float* __restrict__ hs,
                           float* __restrict__ ys) {
  int g = blockIdx.x * 256 + threadIdx.x;
  int n = g & 15;
  int chunk = (g >> 4) & 63;
  int kd = g >> 10;
  int k = kd / 192, d = kd - k * 192;
  const float* ub = ((k & 1) ? xconvT : xconv) + d * LTOK;
  bool rev = (k >= 2);
  float A = -__expf(A_logs[kd * NST + n]);
  const float* dp = delta + kd * LTOK;
  const float* bp = Bm + k * LTOK * NST + n;
  const float* cp = Cm + k * LTOK * NST + n;
  float Dv = Ds[kd];
  float h = hs[(kd * 64 + chunk) * NST + n];
  float* yk = ys + k * (LTOK * DIN_);
  int l0 = chunk * 64;
  for (int t = 0; t < 64; ++t) {
    int l = l0 + t;
    float dlt = dp[l];
    float u = ub[rev ? 4095 - l : l];
    float a = __expf(dlt * A);
    float b = dlt * bp[l * NST] * u;
    h = a * h + b;
    float p = h * cp[l * NST];
    p += __shfl_xor(p, 1);
    p += __shfl_xor(p, 2);
    p += __shfl_xor(p, 4);
    p += __shfl_xor(p, 8);
    if (n == 0) yk[l * DIN_ + d] = p + Dv * u;
  }
}

// K6: combine 4 directions + LN(outn) + *silu(z) + out_proj + residual adds.
// 4 tokens per block (one wave each).
__global__ void combine_kernel(const float* __restrict__ ys, const float* __restrict__ xz,
                               const float* __restrict__ xn, const float* __restrict__ xsrc,
                               const float* __restrict__ og, const float* __restrict__ ob,
                               const float* __restrict__ ow, float* __restrict__ xout) {
  int tid = threadIdx.x;
  int wid = tid >> 6, lane = tid & 63;
  int l = blockIdx.x * 4 + wid;
  int Tl = ((l & 63) << 6) | (l >> 6);
  int l2 = 4095 - l, l3 = 4095 - Tl;
  const float* y0 = ys;
  const float* y1 = ys + LTOK * DIN_;
  const float* y2 = ys + 2 * LTOK * DIN_;
  const float* y3 = ys + 3 * LTOK * DIN_;
  float yv[3];
  float s = 0.f, ss = 0.f;
#pragma unroll
  for (int j = 0; j < 3; ++j) {
    int d = lane + 64 * j;
    float v = y0[l * DIN_ + d] + y1[Tl * DIN_ + d] + y2[l2 * DIN_ + d] + y3[l3 * DIN_ + d];
    yv[j] = v;
    s += v;
    ss += v * v;
  }
  for (int off = 32; off > 0; off >>= 1) { s += __shfl_xor(s, off); ss += __shfl_xor(ss, off); }
  float m = s * (1.f / 192.f);
  float var = ss * (1.f / 192.f) - m * m;
  float rs = rsqrtf(var + 1e-5f);
  __shared__ float lds[4][192];
#pragma unroll
  for (int j = 0; j < 3; ++j) {
    int d = lane + 64 * j;
    float yn = (yv[j] - m) * rs * og[d] + ob[d];
    float z = xz[l * 384 + 192 + d];
    lds[wid][d] = yn * siluf(z);
  }
  __syncthreads();
  float acc0 = 0.f, acc1 = 0.f;
  const float* ldp = lds[wid];
  const float* w0 = ow + lane * DIN_;
  const float* w1 = ow + (lane + 64) * DIN_;
  for (int d = 0; d < DIN_; ++d) {
    float yd = ldp[d];
    acc0 += yd * w0[d];
    if (lane < 32) acc1 += yd * w1[d];
  }
  xout[l * CCH + lane] = xsrc[l * CCH + lane] + xn[l * CCH + lane] + acc0;
  if (lane < 32) {
    int c = lane + 64;
    xout[l * CCH + c] = xsrc[l * CCH + c] + xn[l * CCH + c] + acc1;
  }
}

// K7: final 3x3 full conv (96->96) + bias + global shortcut
// block: (h, 16-wide w tile); threads = 16 c0 x 16 w
__global__ void resconv_kernel(const float* __restrict__ x, const float* __restrict__ w,
                               const float* __restrict__ b, const float* __restrict__ shortcut,
                               float* __restrict__ out) {
  int w0 = blockIdx.x * 16;
  int h = blockIdx.y;
  __shared__ float xs[3][18][97];
  int tid = threadIdx.x;
  for (int idx = tid; idx < 3 * 18 * 96; idx += 256) {
    int c = idx % 96;
    int t = idx / 96;
    int wc = t % 18;
    int r = t / 18;
    int hh = h + r - 1;
    int ww = w0 + wc - 1;
    float v = 0.f;
    if (hh >= 0 && hh < 64 && ww >= 0 && ww < 64) v = x[(hh * 64 + ww) * CCH + c];
    xs[r][wc][c] = v;
  }
  __syncthreads();
  int c0l = tid & 15;
  int wi = tid >> 4;
  int l = h * 64 + w0 + wi;
  for (int cc = 0; cc < 6; ++cc) {
    int c0 = cc * 16 + c0l;
    float acc = b[c0];
    const float* wr = w + c0 * 96 * 9;
    for (int c = 0; c < 96; ++c) {
#pragma unroll
      for (int r = 0; r < 3; ++r)
#pragma unroll
        for (int q = 0; q < 3; ++q)
          acc += xs[r][wi + q][c] * wr[c * 9 + r * 3 + q];
    }
    out[l * CCH + c0] = acc + shortcut[l * CCH + c0];
  }
}

extern "C" void kernel_launch(void* const* d_in, const int* in_sizes, int n_in,
                              void* d_out, int out_size, void* d_ws, size_t ws_size,
                              hipStream_t stream) {
  const float* x_in     = (const float*)d_in[0];
  const float* norm1_g  = (const float*)d_in[3];
  const float* norm1_b  = (const float*)d_in[4];
  const float* vssn_g   = (const float*)d_in[5];
  const float* vssn_b   = (const float*)d_in[6];
  const float* in_proj  = (const float*)d_in[7];
  const float* conv_w   = (const float*)d_in[8];
  const float* conv_b   = (const float*)d_in[9];
  const float* x_proj   = (const float*)d_in[10];
  const float* dt_w     = (const float*)d_in[11];
  const float* dt_b     = (const float*)d_in[12];
  const float* A_logs   = (const float*)d_in[13];
  const float* Ds       = (const float*)d_in[14];
  const float* outn_g   = (const float*)d_in[15];
  const float* outn_b   = (const float*)d_in[16];
  const float* out_proj = (const float*)d_in[17];
  const float* rc_w     = (const float*)d_in[18];
  const float* rc_b     = (const float*)d_in[19];

  float* ws = (float*)d_ws;
  float* xn    = ws + O_XN;
  float* xln   = ws + O_XLN;
  float* xz    = ws + O_XZ;
  float* xconv = ws + O_XCONV;
  float* xconvT= ws + O_XCONVT;
  float* delta = ws + O_DELTA;
  float* Bm    = ws + O_BM;
  float* Cm    = ws + O_CM;
  float* Pb    = ws + O_PB;
  float* qb    = ws + O_QB;
  float* hs    = ws + O_HS;
  float* ysb   = ws + O_YS;
  float* xcur  = ws + O_XCUR;

  const float* xsrc = x_in;
  for (int i = 0; i < 2; ++i) {
    ln2_kernel<<<1024, 256, 0, stream>>>(xsrc, xn, xln,
        norm1_g + i * 96, norm1_b + i * 96, vssn_g + i * 96, vssn_b + i * 96);
    inproj_kernel<<<4096, 128, 0, stream>>>(xln, in_proj + i * 36864, xz);
    dwconv_kernel<<<dim3(64, 6), 256, 0, stream>>>(xz, conv_w + i * 1728, conv_b + i * 192, xconv);
    transpose64_kernel<<<192, 256, 0, stream>>>(xconv, xconvT);
    projdelta_kernel<<<dim3(64, 4), 256, 0, stream>>>(xconv, xconvT,
        x_proj + i * 29184, dt_w + i * 4608, dt_b + i * 768, delta, Bm, Cm);
    scan_pass1<<<3072, 256, 0, stream>>>(delta, Bm, xconv, xconvT, A_logs + i * 12288, Pb, qb);
    scan_pass2<<<48, 256, 0, stream>>>(Pb, qb, hs);
    scan_pass3<<<3072, 256, 0, stream>>>(delta, Bm, Cm, xconv, xconvT,
        A_logs + i * 12288, Ds + i * 768, hs, ysb);
    combine_kernel<<<1024, 256, 0, stream>>>(ysb, xz, xn, xsrc,
        outn_g + i * 192, outn_b + i * 192, out_proj + i * 18432, xcur);
    xsrc = xcur;
  }
  resconv_kernel<<<dim3(4, 64), 256, 0, stream>>>(xcur, rc_w, rc_b, x_in, (float*)d_out);
}

// Round 2
// 869.557 us; speedup vs baseline: 1.1544x; 1.1544x over previous
//
#include <hip/hip_runtime.h>
#include <math.h>

// Problem constants (B=1)
#define LTOK 4096   // H*W tokens
#define CCH  96     // C
#define DIN_ 192
#define KDIR 4
#define NST  16
#define RRK  6
#define KD_  768    // K*DIN

// ---------------- workspace layout (floats) ----------------
#define O_XN     0
#define O_XLN    393216
#define O_XZ     786432      // 4096*384
#define O_XCONV  2359296     // 192*4096
#define O_XCONVT 3145728
#define O_DELTA  3932160     // 768*4096  (scan-order per kd); reused as resconv pbuf
#define O_BM     7077888     // 4*4096*16 (k,l,n)
#define O_CM     7340032
#define O_PB     7602176     // 768*64*16 ; reused as yg (4096*192) after scans
#define O_QB     8388608
#define O_HS     9175040
#define O_YS     9961472     // 4*4096*192 (k, scanpos, d)
#define O_XCUR   13107200
// total 13500416 floats = ~51.5 MB

__device__ __forceinline__ float siluf(float x) { return x / (1.f + __expf(-x)); }

// K1: double layernorm per token (C=96). 4 tokens per 256-block, one wave each.
__global__ void ln2_kernel(const float* __restrict__ x, float* __restrict__ xn, float* __restrict__ xln,
                           const float* __restrict__ g1, const float* __restrict__ b1,
                           const float* __restrict__ g2, const float* __restrict__ b2) {
  int tid = threadIdx.x, wid = tid >> 6, lane = tid & 63;
  int l = blockIdx.x * 4 + wid;
  const float* xr = x + l * CCH;
  float v0 = xr[lane];
  float v1 = (lane < 32) ? xr[64 + lane] : 0.f;
  float s = v0 + v1, ss = v0 * v0 + v1 * v1;
  for (int off = 32; off > 0; off >>= 1) { s += __shfl_xor(s, off); ss += __shfl_xor(ss, off); }
  float m = s * (1.f / 96.f);
  float rs = rsqrtf(ss * (1.f / 96.f) - m * m + 1e-5f);
  float n0 = (v0 - m) * rs * g1[lane] + b1[lane];
  float n1 = (lane < 32) ? (v1 - m) * rs * g1[64 + lane] + b1[64 + lane] : 0.f;
  xn[l * CCH + lane] = n0;
  if (lane < 32) xn[l * CCH + 64 + lane] = n1;
  float s2 = n0 + n1, ss2 = n0 * n0 + n1 * n1;
  for (int off = 32; off > 0; off >>= 1) { s2 += __shfl_xor(s2, off); ss2 += __shfl_xor(ss2, off); }
  float m2 = s2 * (1.f / 96.f);
  float rs2 = rsqrtf(ss2 * (1.f / 96.f) - m2 * m2 + 1e-5f);
  xln[l * CCH + lane] = (n0 - m2) * rs2 * g2[lane] + b2[lane];
  if (lane < 32) xln[l * CCH + 64 + lane] = (n1 - m2) * rs2 * g2[64 + lane] + b2[64 + lane];
}

// K2: in_proj as tiled GEMM. out xz[l][j] = sum_c xln[l][c]*w[j][c].
// Tile 64 tokens x 64 outputs, K=96. grid (64, 6), block 256.
__global__ void inproj_gemm(const float* __restrict__ xln, const float* __restrict__ w,
                            float* __restrict__ xz) {
  __shared__ float As[96 * 65];  // As[k*65 + m]
  __shared__ float Bs[96 * 65];  // Bs[k*65 + n]
  int tid = threadIdx.x;
  int l0 = blockIdx.x * 64, j0 = blockIdx.y * 64;
  // stage A: 64 tokens x 24 float4 quads
  for (int qi = tid; qi < 64 * 24; qi += 256) {
    int m = qi / 24, q = qi % 24;
    const float4 v = *(const float4*)&xln[(l0 + m) * 96 + q * 4];
    As[(q * 4 + 0) * 65 + m] = v.x;
    As[(q * 4 + 1) * 65 + m] = v.y;
    As[(q * 4 + 2) * 65 + m] = v.z;
    As[(q * 4 + 3) * 65 + m] = v.w;
  }
  for (int qi = tid; qi < 64 * 24; qi += 256) {
    int n = qi / 24, q = qi % 24;
    const float4 v = *(const float4*)&w[(j0 + n) * 96 + q * 4];
    Bs[(q * 4 + 0) * 65 + n] = v.x;
    Bs[(q * 4 + 1) * 65 + n] = v.y;
    Bs[(q * 4 + 2) * 65 + n] = v.z;
    Bs[(q * 4 + 3) * 65 + n] = v.w;
  }
  __syncthreads();
  int mg = tid & 15, ng = tid >> 4;
  float acc[4][4] = {};
  for (int k = 0; k < 96; ++k) {
    float a0 = As[k * 65 + 4 * mg + 0], a1 = As[k * 65 + 4 * mg + 1];
    float a2 = As[k * 65 + 4 * mg + 2], a3 = As[k * 65 + 4 * mg + 3];
    float b0 = Bs[k * 65 + 4 * ng + 0], b1 = Bs[k * 65 + 4 * ng + 1];
    float b2 = Bs[k * 65 + 4 * ng + 2], b3 = Bs[k * 65 + 4 * ng + 3];
    acc[0][0] += a0 * b0; acc[0][1] += a0 * b1; acc[0][2] += a0 * b2; acc[0][3] += a0 * b3;
    acc[1][0] += a1 * b0; acc[1][1] += a1 * b1; acc[1][2] += a1 * b2; acc[1][3] += a1 * b3;
    acc[2][0] += a2 * b0; acc[2][1] += a2 * b1; acc[2][2] += a2 * b2; acc[2][3] += a2 * b3;
    acc[3][0] += a3 * b0; acc[3][1] += a3 * b1; acc[3][2] += a3 * b2; acc[3][3] += a3 * b3;
  }
#pragma unroll
  for (int i = 0; i < 4; ++i) {
    float4 o = make_float4(acc[i][0], acc[i][1], acc[i][2], acc[i][3]);
    *(float4*)&xz[(l0 + 4 * mg + i) * 384 + j0 + 4 * ng] = o;
  }
}

// K3: depthwise 3x3 conv + bias + silu.  Output channel-major xconv[d][l].
__global__ void dwconv_kernel(const float* __restrict__ xz, const float* __restrict__ cw,
                              const float* __restrict__ cb, float* __restrict__ xconv) {
  int h = blockIdx.x;
  int d0 = blockIdx.y * 32;
  __shared__ float xs[3][64][33];
  int tid = threadIdx.x;
  for (int idx = tid; idx < 3 * 64 * 32; idx += 256) {
    int dd = idx & 31;
    int w = (idx >> 5) & 63;
    int r = idx >> 11;
    int hh = h + r - 1;
    float v = 0.f;
    if (hh >= 0 && hh < 64) v = xz[(hh * 64 + w) * 384 + d0 + dd];
    xs[r][w][dd] = v;
  }
  __syncthreads();
  int w = tid & 63;
  int dsub = tid >> 6;
  for (int dd = dsub; dd < 32; dd += 4) {
    int d = d0 + dd;
    float acc = cb[d];
    const float* wgt = cw + d * 9;
#pragma unroll
    for (int r = 0; r < 3; ++r)
#pragma unroll
      for (int c = 0; c < 3; ++c) {
        int ww = w + c - 1;
        if (ww >= 0 && ww < 64) acc += xs[r][ww][dd] * wgt[r * 3 + c];
      }
    xconv[d * LTOK + h * 64 + w] = siluf(acc);
  }
}

// K3T: per-channel 64x64 transpose.
__global__ void transpose64_kernel(const float* __restrict__ in, float* __restrict__ out) {
  int d = blockIdx.x;
  __shared__ float t[64][65];
  const float* src = in + d * LTOK;
  float* dst = out + d * LTOK;
  int tid = threadIdx.x;
  for (int idx = tid; idx < 4096; idx += 256) {
    int w = idx & 63, h = idx >> 6;
    t[h][w] = src[idx];
  }
  __syncthreads();
  for (int idx = tid; idx < 4096; idx += 256) {
    int hh = idx & 63, ww = idx >> 6;
    dst[idx] = t[hh][ww];
  }
}

// K4: x_proj + dt proj + softplus.
__global__ void projdelta_kernel(const float* __restrict__ xconv, const float* __restrict__ xconvT,
                                 const float* __restrict__ xpw, const float* __restrict__ dtw,
                                 const float* __restrict__ dtb, float* __restrict__ delta,
                                 float* __restrict__ Bm, float* __restrict__ Cm) {
  int chunk = blockIdx.x;
  int k = blockIdx.y;
  int l0 = chunk * 64;
  __shared__ float xsm[192 * 64];
  __shared__ float xdm[38 * 64];
  int tid = threadIdx.x;
  const float* ub = ((k & 1) ? xconvT : xconv);
  bool rev = (k >= 2);
  for (int idx = tid; idx < 192 * 64; idx += 256) {
    int i = idx & 63, d = idx >> 6;
    int l = l0 + i;
    xsm[idx] = ub[d * LTOK + (rev ? 4095 - l : l)];
  }
  __syncthreads();
  for (int o = tid; o < 38 * 64; o += 256) {
    int i = o & 63, c = o >> 6;
    const float* wr = xpw + (k * 38 + c) * 192;
    float acc = 0.f;
#pragma unroll 8
    for (int d = 0; d < 192; ++d) acc += wr[d] * xsm[d * 64 + i];
    xdm[o] = acc;
    if (c >= 6) {
      int l = l0 + i;
      if (c < 22) Bm[(k * LTOK + l) * NST + (c - 6)] = acc;
      else        Cm[(k * LTOK + l) * NST + (c - 22)] = acc;
    }
  }
  __syncthreads();
  for (int o = tid; o < 192 * 64; o += 256) {
    int i = o & 63, d = o >> 6;
    float acc = dtb[k * 192 + d];
    const float* wr = dtw + (k * 192 + d) * 6;
#pragma unroll
    for (int r = 0; r < 6; ++r) acc += xdm[r * 64 + i] * wr[r];
    float sp = (acc > 20.f) ? acc : log1pf(__expf(acc));
    delta[(k * 192 + d) * LTOK + l0 + i] = sp;
  }
}

// Scan pass 1
__global__ void scan_pass1(const float* __restrict__ delta, const float* __restrict__ Bm,
                           const float* __restrict__ xconv, const float* __restrict__ xconvT,
                           const float* __restrict__ A_logs, float* __restrict__ Pb,
                           float* __restrict__ qb) {
  int g = blockIdx.x * 256 + threadIdx.x;
  int n = g & 15;
  int chunk = (g >> 4) & 63;
  int kd = g >> 10;
  int k = kd / 192, d = kd - k * 192;
  const float* ub = ((k & 1) ? xconvT : xconv) + d * LTOK;
  bool rev = (k >= 2);
  float A = -__expf(A_logs[kd * NST + n]);
  const float* dp = delta + kd * LTOK;
  const float* bp = Bm + k * LTOK * NST + n;
  float P = 1.f, q = 0.f;
  int l0 = chunk * 64;
  for (int t = 0; t < 64; ++t) {
    int l = l0 + t;
    float dlt = dp[l];
    float u = ub[rev ? 4095 - l : l];
    float a = __expf(dlt * A);
    float b = dlt * bp[l * NST] * u;
    q = a * q + b;
    P *= a;
  }
  int o = (kd * 64 + chunk) * NST + n;
  Pb[o] = P;
  qb[o] = q;
}

// Scan pass 2
__global__ void scan_pass2(const float* __restrict__ Pb, const float* __restrict__ qb,
                           float* __restrict__ hs) {
  int g = blockIdx.x * 256 + threadIdx.x;  // 12288 threads
  int n = g & 15, kd = g >> 4;
  float h = 0.f;
  for (int c = 0; c < 64; ++c) {
    int o = (kd * 64 + c) * NST + n;
    hs[o] = h;
    h = Pb[o] * h + qb[o];
  }
}

// Scan pass 3
__global__ void scan_pass3(const float* __restrict__ delta, const float* __restrict__ Bm,
                           const float* __restrict__ Cm, const float* __restrict__ xconv,
                           const float* __restrict__ xconvT, const float* __restrict__ A_logs,
                           const float* __restrict__ Ds, const float* __restrict__ hs,
                           float* __restrict__ ys) {
  int g = blockIdx.x * 256 + threadIdx.x;
  int n = g & 15;
  int chunk = (g >> 4) & 63;
  int kd = g >> 10;
  int k = kd / 192, d = kd - k * 192;
  const float* ub = ((k & 1) ? xconvT : xconv) + d * LTOK;
  bool rev = (k >= 2);
  float A = -__expf(A_logs[kd * NST + n]);
  const float* dp = delta + kd * LTOK;
  const float* bp = Bm + k * LTOK * NST + n;
  const float* cp = Cm + k * LTOK * NST + n;
  float Dv = Ds[kd];
  float h = hs[(kd * 64 + chunk) * NST + n];
  float* yk = ys + k * (LTOK * DIN_);
  int l0 = chunk * 64;
  for (int t = 0; t < 64; ++t) {
    int l = l0 + t;
    float dlt = dp[l];
    float u = ub[rev ? 4095 - l : l];
    float a = __expf(dlt * A);
    float b = dlt * bp[l * NST] * u;
    h = a * h + b;
    float p = h * cp[l * NST];
    p += __shfl_xor(p, 1);
    p += __shfl_xor(p, 2);
    p += __shfl_xor(p, 4);
    p += __shfl_xor(p, 8);
    if (n == 0) yk[l * DIN_ + d] = p + Dv * u;
  }
}

// K6a: combine 4 directions + LN(outn) + *silu(z) -> yg[l][d]
__global__ void combine_pre(const float* __restrict__ ys, const float* __restrict__ xz,
                            const float* __restrict__ og, const float* __restrict__ ob,
                            float* __restrict__ yg) {
  int tid = threadIdx.x;
  int wid = tid >> 6, lane = tid & 63;
  int l = blockIdx.x * 4 + wid;
  int Tl = ((l & 63) << 6) | (l >> 6);
  int l2 = 4095 - l, l3 = 4095 - Tl;
  const float* y0 = ys;
  const float* y1 = ys + LTOK * DIN_;
  const float* y2 = ys + 2 * LTOK * DIN_;
  const float* y3 = ys + 3 * LTOK * DIN_;
  float yv[3];
  float s = 0.f, ss = 0.f;
#pragma unroll
  for (int j = 0; j < 3; ++j) {
    int d = lane + 64 * j;
    float v = y0[l * DIN_ + d] + y1[Tl * DIN_ + d] + y2[l2 * DIN_ + d] + y3[l3 * DIN_ + d];
    yv[j] = v;
    s += v;
    ss += v * v;
  }
  for (int off = 32; off > 0; off >>= 1) { s += __shfl_xor(s, off); ss += __shfl_xor(ss, off); }
  float m = s * (1.f / 192.f);
  float var = ss * (1.f / 192.f) - m * m;
  float rs = rsqrtf(var + 1e-5f);
#pragma unroll
  for (int j = 0; j < 3; ++j) {
    int d = lane + 64 * j;
    float yn = (yv[j] - m) * rs * og[d] + ob[d];
    float z = xz[l * 384 + 192 + d];
    yg[l * DIN_ + d] = yn * siluf(z);
  }
}

// K6b: out_proj GEMM + residuals. xout[l][c] = xsrc + xn + sum_d yg[l][d]*ow[c][d]
// tile 64 tokens x 32 outputs, K=192 in 3 chunks of 64. grid (64, 3), block 256.
__global__ void outproj_gemm(const float* __restrict__ yg, const float* __restrict__ ow,
                             const float* __restrict__ xn, const float* __restrict__ xsrc,
                             float* __restrict__ xout) {
  __shared__ float As[64 * 65];  // As[k*65 + m]
  __shared__ float Bs[64 * 33];  // Bs[k*33 + n]
  int tid = threadIdx.x;
  int l0 = blockIdx.x * 64, n0 = blockIdx.y * 32;
  int mg = tid & 15, ng = tid >> 4;
  float acc[4][2] = {};
  for (int kc = 0; kc < 3; ++kc) {
    __syncthreads();
    for (int qi = tid; qi < 64 * 16; qi += 256) {
      int m = qi / 16, q = qi % 16;
      const float4 v = *(const float4*)&yg[(l0 + m) * 192 + kc * 64 + q * 4];
      As[(q * 4 + 0) * 65 + m] = v.x;
      As[(q * 4 + 1) * 65 + m] = v.y;
      As[(q * 4 + 2) * 65 + m] = v.z;
      As[(q * 4 + 3) * 65 + m] = v.w;
    }
    for (int qi = tid; qi < 32 * 16; qi += 256) {
      int n = qi / 16, q = qi % 16;
      const float4 v = *(const float4*)&ow[(n0 + n) * 192 + kc * 64 + q * 4];
      Bs[(q * 4 + 0) * 33 + n] = v.x;
      Bs[(q * 4 + 1) * 33 + n] = v.y;
      Bs[(q * 4 + 2) * 33 + n] = v.z;
      Bs[(q * 4 + 3) * 33 + n] = v.w;
    }
    __syncthreads();
    for (int k = 0; k < 64; ++k) {
      float a0 = As[k * 65 + 4 * mg + 0], a1 = As[k * 65 + 4 * mg + 1];
      float a2 = As[k * 65 + 4 * mg + 2], a3 = As[k * 65 + 4 * mg + 3];
      float b0 = Bs[k * 33 + 2 * ng + 0], b1 = Bs[k * 33 + 2 * ng + 1];
      acc[0][0] += a0 * b0; acc[0][1] += a0 * b1;
      acc[1][0] += a1 * b0; acc[1][1] += a1 * b1;
      acc[2][0] += a2 * b0; acc[2][1] += a2 * b1;
      acc[3][0] += a3 * b0; acc[3][1] += a3 * b1;
    }
  }
#pragma unroll
  for (int i = 0; i < 4; ++i) {
    int l = l0 + 4 * mg + i;
#pragma unroll
    for (int jj = 0; jj < 2; ++jj) {
      int c = n0 + 2 * ng + jj;
      xout[l * 96 + c] = xsrc[l * 96 + c] + xn[l * 96 + c] + acc[i][jj];
    }
  }
}

// K7a: final 3x3 conv partials. grid (64 tiles, 8 c-slices), block 256.
// Lanes = 8x8 token tile; tid>>6 selects 24-wide c0 group (wave-uniform -> s_load weights).
__global__ void resconv_part(const float* __restrict__ x, const float* __restrict__ w,
                             float* __restrict__ pbuf) {
  int tile = blockIdx.x;
  int cs = blockIdx.y;
  int th0 = (tile >> 3) * 8, tw0 = (tile & 7) * 8;
  int cbase = cs * 12;
  __shared__ float xs[12][10][10];
  int tid = threadIdx.x;
  for (int idx = tid; idx < 12 * 100; idx += 256) {
    int cc = idx % 12;
    int pos = idx / 12;
    int hh = th0 + pos / 10 - 1;
    int ww = tw0 + pos % 10 - 1;
    float v = 0.f;
    if (hh >= 0 && hh < 64 && ww >= 0 && ww < 64) v = x[(hh * 64 + ww) * 96 + cbase + cc];
    xs[cc][pos / 10][pos % 10] = v;
  }
  __syncthreads();
  int lane = tid & 63;
  int th = lane >> 3, tw = lane & 7;
  int c0g = __builtin_amdgcn_readfirstlane(tid >> 6);  // wave-uniform 0..3
  float acc[24] = {};
  for (int cc = 0; cc < 12; ++cc) {
    float xv[9];
#pragma unroll
    for (int r = 0; r < 3; ++r)
#pragma unroll
      for (int q = 0; q < 3; ++q) xv[r * 3 + q] = xs[cc][th + r][tw + q];
    const float* wp = w + (c0g * 24) * 864 + (cbase + cc) * 9;
#pragma unroll 4
    for (int j = 0; j < 24; ++j) {
#pragma unroll
      for (int t = 0; t < 9; ++t) acc[j] += xv[t] * wp[j * 864 + t];
    }
  }
  int l = (th0 + th) * 64 + tw0 + tw;
  float* pb = pbuf + cs * 393216 + l * 96 + c0g * 24;
#pragma unroll
  for (int j = 0; j < 24; ++j) pb[j] = acc[j];
}

// K7b: reduce 8 partials + bias + global shortcut
__global__ void resconv_reduce(const float* __restrict__ pbuf, const float* __restrict__ b,
                               const float* __restrict__ shortcut, float* __restrict__ out) {
  int idx = blockIdx.x * 256 + threadIdx.x;  // < 393216
  int c0 = idx % 96;
  float s = shortcut[idx] + b[c0];
#pragma unroll
  for (int ss = 0; ss < 8; ++ss) s += pbuf[ss * 393216 + idx];
  out[idx] = s;
}

extern "C" void kernel_launch(void* const* d_in, const int* in_sizes, int n_in,
                              void* d_out, int out_size, void* d_ws, size_t ws_size,
                              hipStream_t stream) {
  const float* x_in     = (const float*)d_in[0];
  const float* norm1_g  = (const float*)d_in[3];
  const float* norm1_b  = (const float*)d_in[4];
  const float* vssn_g   = (const float*)d_in[5];
  const float* vssn_b   = (const float*)d_in[6];
  const float* in_proj  = (const float*)d_in[7];
  const float* conv_w   = (const float*)d_in[8];
  const float* conv_b   = (const float*)d_in[9];
  const float* x_proj   = (const float*)d_in[10];
  const float* dt_w     = (const float*)d_in[11];
  const float* dt_b     = (const float*)d_in[12];
  const float* A_logs   = (const float*)d_in[13];
  const float* Ds       = (const float*)d_in[14];
  const float* outn_g   = (const float*)d_in[15];
  const float* outn_b   = (const float*)d_in[16];
  const float* out_proj = (const float*)d_in[17];
  const float* rc_w     = (const float*)d_in[18];
  const float* rc_b     = (const float*)d_in[19];

  float* ws = (float*)d_ws;
  float* xn    = ws + O_XN;
  float* xln   = ws + O_XLN;
  float* xz    = ws + O_XZ;
  float* xconv = ws + O_XCONV;
  float* xconvT= ws + O_XCONVT;
  float* delta = ws + O_DELTA;
  float* Bm    = ws + O_BM;
  float* Cm    = ws + O_CM;
  float* Pb    = ws + O_PB;
  float* qb    = ws + O_QB;
  float* hs    = ws + O_HS;
  float* ysb   = ws + O_YS;
  float* xcur  = ws + O_XCUR;
  float* yg    = ws + O_PB;     // reuse (Pb dead after scan_pass2 consumers)
  float* pbuf  = ws + O_DELTA;  // reuse (delta dead after layer-2 scan_pass3)

  const float* xsrc = x_in;
  for (int i = 0; i < 2; ++i) {
    ln2_kernel<<<1024, 256, 0, stream>>>(xsrc, xn, xln,
        norm1_g + i * 96, norm1_b + i * 96, vssn_g + i * 96, vssn_b + i * 96);
    inproj_gemm<<<dim3(64, 6), 256, 0, stream>>>(xln, in_proj + i * 36864, xz);
    dwconv_kernel<<<dim3(64, 6), 256, 0, stream>>>(xz, conv_w + i * 1728, conv_b + i * 192, xconv);
    transpose64_kernel<<<192, 256, 0, stream>>>(xconv, xconvT);
    projdelta_kernel<<<dim3(64, 4), 256, 0, stream>>>(xconv, xconvT,
        x_proj + i * 29184, dt_w + i * 4608, dt_b + i * 768, delta, Bm, Cm);
    scan_pass1<<<3072, 256, 0, stream>>>(delta, Bm, xconv, xconvT, A_logs + i * 12288, Pb, qb);
    scan_pass2<<<48, 256, 0, stream>>>(Pb, qb, hs);
    scan_pass3<<<3072, 256, 0, stream>>>(delta, Bm, Cm, xconv, xconvT,
        A_logs + i * 12288, Ds + i * 768, hs, ysb);
    combine_pre<<<1024, 256, 0, stream>>>(ysb, xz, outn_g + i * 192, outn_b + i * 192, yg);
    outproj_gemm<<<dim3(64, 3), 256, 0, stream>>>(yg, out_proj + i * 18432, xn, xsrc, xcur);
    xsrc = xcur;
  }
  resconv_part<<<dim3(64, 8), 256, 0, stream>>>(xcur, rc_w, pbuf);
  resconv_reduce<<<1536, 256, 0, stream>>>(pbuf, rc_b, x_in, (float*)d_out);
}

// Round 3
// 736.658 us; speedup vs baseline: 1.3626x; 1.1804x over previous
//
#include <hip/hip_runtime.h>
#include <math.h>

// Problem constants (B=1)
#define LTOK 4096   // H*W tokens
#define CCH  96     // C
#define DIN_ 192
#define KDIR 4
#define NST  16
#define KD_  768    // K*DIN

// ---------------- workspace layout (floats) ----------------
#define O_XN     0
#define O_XZ     786432      // 4096*384
#define O_XCONV  2359296     // 192*4096
#define O_XCONVT 3145728
#define O_DELTA  3932160     // 768*4096 (scan order); reused as resconv pbuf at end
#define O_BM     7077888     // 4*4096*16 (k,l,n)
#define O_CM     7340032
#define O_YS     9961472     // 4*4096*192 (k, scanpos, d)
#define O_XCUR   13107200
// total 13500416 floats = ~51.5 MB

__device__ __forceinline__ float siluf(float x) { return x / (1.f + __expf(-x)); }

// ============ A: LN1 + LN2 + in_proj GEMM ============
// grid (64, 2), block 256. Block: 64 tokens; by selects 3 of 6 output chunks of 64.
__global__ void fusedA_kernel(const float* __restrict__ x, const float* __restrict__ g1,
                              const float* __restrict__ b1, const float* __restrict__ g2,
                              const float* __restrict__ b2, const float* __restrict__ w,
                              float* __restrict__ xn, float* __restrict__ xz) {
  __shared__ float As[96 * 72];  // As[k*72 + m] : LN2 output, k-major
  __shared__ float Bs[96 * 68];  // Bs[k*68 + n]
  int tid = threadIdx.x;
  int l0 = blockIdx.x * 64;
  int m = tid >> 2, j = tid & 3;       // token m (0..63), quad lane j
  int l = l0 + m;
  float v[24];
  float s = 0.f, ss = 0.f;
#pragma unroll
  for (int t = 0; t < 24; ++t) {
    int k = j + 4 * t;
    float vv = x[l * 96 + k];
    v[t] = vv; s += vv; ss += vv * vv;
  }
  s += __shfl_xor(s, 1); ss += __shfl_xor(ss, 1);
  s += __shfl_xor(s, 2); ss += __shfl_xor(ss, 2);
  float m1 = s * (1.f / 96.f);
  float rs1 = rsqrtf(ss * (1.f / 96.f) - m1 * m1 + 1e-5f);
  float s2 = 0.f, ss2 = 0.f;
#pragma unroll
  for (int t = 0; t < 24; ++t) {
    int k = j + 4 * t;
    float nv = (v[t] - m1) * rs1 * g1[k] + b1[k];
    v[t] = nv; s2 += nv; ss2 += nv * nv;
    if (blockIdx.y == 0) xn[l * 96 + k] = nv;
  }
  s2 += __shfl_xor(s2, 1); ss2 += __shfl_xor(ss2, 1);
  s2 += __shfl_xor(s2, 2); ss2 += __shfl_xor(ss2, 2);
  float m2 = s2 * (1.f / 96.f);
  float rs2 = rsqrtf(ss2 * (1.f / 96.f) - m2 * m2 + 1e-5f);
#pragma unroll
  for (int t = 0; t < 24; ++t) {
    int k = j + 4 * t;
    As[k * 72 + m] = (v[t] - m2) * rs2 * g2[k] + b2[k];
  }
  int mg = tid & 15, ng = tid >> 4;
  for (int cc = 0; cc < 3; ++cc) {
    int j0 = (blockIdx.y * 3 + cc) * 64;
    __syncthreads();
    for (int qi = tid; qi < 64 * 24; qi += 256) {
      int nn = qi / 24, q = qi % 24;
      const float4 wv = *(const float4*)&w[(j0 + nn) * 96 + q * 4];
      Bs[(q * 4 + 0) * 68 + nn] = wv.x;
      Bs[(q * 4 + 1) * 68 + nn] = wv.y;
      Bs[(q * 4 + 2) * 68 + nn] = wv.z;
      Bs[(q * 4 + 3) * 68 + nn] = wv.w;
    }
    __syncthreads();
    float acc[4][4] = {};
    for (int k = 0; k < 96; ++k) {
      float a0 = As[k * 72 + 4 * mg + 0], a1 = As[k * 72 + 4 * mg + 1];
      float a2 = As[k * 72 + 4 * mg + 2], a3 = As[k * 72 + 4 * mg + 3];
      float b0 = Bs[k * 68 + 4 * ng + 0], b1_ = Bs[k * 68 + 4 * ng + 1];
      float b2_ = Bs[k * 68 + 4 * ng + 2], b3 = Bs[k * 68 + 4 * ng + 3];
      acc[0][0] += a0 * b0; acc[0][1] += a0 * b1_; acc[0][2] += a0 * b2_; acc[0][3] += a0 * b3;
      acc[1][0] += a1 * b0; acc[1][1] += a1 * b1_; acc[1][2] += a1 * b2_; acc[1][3] += a1 * b3;
      acc[2][0] += a2 * b0; acc[2][1] += a2 * b1_; acc[2][2] += a2 * b2_; acc[2][3] += a2 * b3;
      acc[3][0] += a3 * b0; acc[3][1] += a3 * b1_; acc[3][2] += a3 * b2_; acc[3][3] += a3 * b3;
    }
#pragma unroll
    for (int i = 0; i < 4; ++i) {
      float4 o = make_float4(acc[i][0], acc[i][1], acc[i][2], acc[i][3]);
      *(float4*)&xz[(l0 + 4 * mg + i) * 384 + j0 + 4 * ng] = o;
    }
  }
}

// ============ B: depthwise conv 3x3 + silu, writes xconv AND xconvT ============
// grid (4,4,6): w-tile, h-tile, d-tile(32). block 256 = 16h x 16w.
__global__ void dwconvT_kernel(const float* __restrict__ xz, const float* __restrict__ cw,
                               const float* __restrict__ cb, float* __restrict__ xconv,
                               float* __restrict__ xconvT) {
  int w0 = blockIdx.x * 16, h0 = blockIdx.y * 16, d0 = blockIdx.z * 32;
  __shared__ float xs[324 * 33];  // [pos(18x18)][dd]
  int tid = threadIdx.x;
  for (int idx = tid; idx < 324 * 32; idx += 256) {
    int dd = idx & 31;
    int p = idx >> 5;
    int ph = p / 18, pw = p - ph * 18;
    int hh = h0 + ph - 1, ww = w0 + pw - 1;
    float v = 0.f;
    if (hh >= 0 && hh < 64 && ww >= 0 && ww < 64) v = xz[(hh * 64 + ww) * 384 + d0 + dd];
    xs[p * 33 + dd] = v;
  }
  __syncthreads();
  int wi = tid & 15, hi = tid >> 4;
  for (int dd = 0; dd < 32; ++dd) {
    int d = d0 + dd;
    float acc = cb[d];
    const float* wgt = cw + d * 9;
#pragma unroll
    for (int r = 0; r < 3; ++r)
#pragma unroll
      for (int c = 0; c < 3; ++c)
        acc += xs[((hi + r) * 18 + wi + c) * 33 + dd] * wgt[r * 3 + c];
    float o = siluf(acc);
    xconv[d * LTOK + (h0 + hi) * 64 + w0 + wi] = o;
    xconvT[d * LTOK + (w0 + wi) * 64 + h0 + hi] = o;
  }
}

// ============ C: x_proj + dt proj + softplus ============
__global__ void projdelta_kernel(const float* __restrict__ xconv, const float* __restrict__ xconvT,
                                 const float* __restrict__ xpw, const float* __restrict__ dtw,
                                 const float* __restrict__ dtb, float* __restrict__ delta,
                                 float* __restrict__ Bm, float* __restrict__ Cm) {
  int chunk = blockIdx.x;
  int k = blockIdx.y;
  int l0 = chunk * 64;
  __shared__ float xsm[192 * 64];
  __shared__ float xdm[38 * 64];
  int tid = threadIdx.x;
  const float* ub = ((k & 1) ? xconvT : xconv);
  bool rev = (k >= 2);
  for (int idx = tid; idx < 192 * 64; idx += 256) {
    int i = idx & 63, d = idx >> 6;
    int l = l0 + i;
    xsm[idx] = ub[d * LTOK + (rev ? 4095 - l : l)];
  }
  __syncthreads();
  for (int o = tid; o < 38 * 64; o += 256) {
    int i = o & 63, c = o >> 6;
    const float* wr = xpw + (k * 38 + c) * 192;
    float acc = 0.f;
#pragma unroll 8
    for (int d = 0; d < 192; ++d) acc += wr[d] * xsm[d * 64 + i];
    xdm[o] = acc;
    if (c >= 6) {
      int l = l0 + i;
      if (c < 22) Bm[(k * LTOK + l) * NST + (c - 6)] = acc;
      else        Cm[(k * LTOK + l) * NST + (c - 22)] = acc;
    }
  }
  __syncthreads();
  for (int o = tid; o < 192 * 64; o += 256) {
    int i = o & 63, d = o >> 6;
    float acc = dtb[k * 192 + d];
    const float* wr = dtw + (k * 192 + d) * 6;
#pragma unroll
    for (int r = 0; r < 6; ++r) acc += xdm[r * 64 + i] * wr[r];
    float sp = (acc > 20.f) ? acc : log1pf(__expf(acc));
    delta[(k * 192 + d) * LTOK + l0 + i] = sp;
  }
}

// ============ D: full selective scan in ONE kernel. block = one kd channel. ============
// 768 blocks x 256 threads. thread: n = tid&15, chunk-quad cq = tid>>4.
__global__ void scan_fused(const float* __restrict__ delta, const float* __restrict__ Bm,
                           const float* __restrict__ Cm, const float* __restrict__ xconv,
                           const float* __restrict__ xconvT, const float* __restrict__ A_logs,
                           const float* __restrict__ Ds, float* __restrict__ ys) {
  int kd = blockIdx.x;
  int k = kd / 192, d = kd - k * 192;
  int tid = threadIdx.x;
  int n = tid & 15, cq = tid >> 4;
  const float* ub = ((k & 1) ? xconvT : xconv) + d * LTOK;
  bool rev = (k >= 2);
  float A = -__expf(A_logs[kd * NST + n]);
  const float* dp = delta + kd * LTOK;
  const float* bp = Bm + (k * LTOK) * NST + n;
  const float* cp = Cm + (k * LTOK) * NST + n;
  __shared__ float Ps[1024], Qs[1024], H0s[1024];
  // phase A: per-chunk (prod a, local end state)
#pragma unroll
  for (int i = 0; i < 4; ++i) {
    int c = cq + 16 * i;
    int l0 = c * 64;
    float P = 1.f, q = 0.f;
    for (int t = 0; t < 64; ++t) {
      int l = l0 + t;
      float dlt = dp[l];
      float u = ub[rev ? 4095 - l : l];
      float a = __expf(dlt * A);
      q = a * q + dlt * bp[l * NST] * u;
      P *= a;
    }
    Ps[c * 16 + n] = P; Qs[c * 16 + n] = q;
  }
  __syncthreads();
  // phase B: inter-chunk scan, 16 threads
  if (tid < 16) {
    float h = 0.f;
    for (int c = 0; c < 64; ++c) {
      H0s[c * 16 + tid] = h;
      h = Ps[c * 16 + tid] * h + Qs[c * 16 + tid];
    }
  }
  __syncthreads();
  // phase C: replay with correct h0, emit y
  float Dv = Ds[kd];
  float* yk = ys + k * (LTOK * DIN_);
#pragma unroll
  for (int i = 0; i < 4; ++i) {
    int c = cq + 16 * i;
    int l0 = c * 64;
    float h = H0s[c * 16 + n];
    for (int t = 0; t < 64; ++t) {
      int l = l0 + t;
      float dlt = dp[l];
      float u = ub[rev ? 4095 - l : l];
      float a = __expf(dlt * A);
      h = a * h + dlt * bp[l * NST] * u;
      float p = h * cp[l * NST];
      p += __shfl_xor(p, 1);
      p += __shfl_xor(p, 2);
      p += __shfl_xor(p, 4);
      p += __shfl_xor(p, 8);
      if (n == 0) yk[l * DIN_ + d] = p + Dv * u;
    }
  }
}

// ============ E: dir-combine + LN + silu-gate + out_proj + residuals ============
// grid 128, block 256. Block: 32 tokens, all 96 outputs.
__global__ void combine_out(const float* __restrict__ ys, const float* __restrict__ xz,
                            const float* __restrict__ xn, const float* __restrict__ xsrc,
                            const float* __restrict__ og, const float* __restrict__ ob,
                            const float* __restrict__ ow, float* __restrict__ xout) {
  __shared__ float Ys[192 * 36];  // [d][m] gated LN output, k-major
  __shared__ float Bs[64 * 100];  // [kk][c]
  int tid = threadIdx.x;
  int l0 = blockIdx.x * 32;
  int m2 = tid >> 3, j = tid & 7;
  int l = l0 + m2;
  int Tl = ((l & 63) << 6) | (l >> 6);
  int l2 = 4095 - l, l3 = 4095 - Tl;
  const float* y0 = ys;
  const float* y1 = ys + LTOK * DIN_;
  const float* y2 = ys + 2 * LTOK * DIN_;
  const float* y3 = ys + 3 * LTOK * DIN_;
  float v[24];
  float s = 0.f, ss = 0.f;
#pragma unroll
  for (int t = 0; t < 24; ++t) {
    int d = j + 8 * t;
    float vv = y0[l * DIN_ + d] + y1[Tl * DIN_ + d] + y2[l2 * DIN_ + d] + y3[l3 * DIN_ + d];
    v[t] = vv; s += vv; ss += vv * vv;
  }
  s += __shfl_xor(s, 1); ss += __shfl_xor(ss, 1);
  s += __shfl_xor(s, 2); ss += __shfl_xor(ss, 2);
  s += __shfl_xor(s, 4); ss += __shfl_xor(ss, 4);
  float mu = s * (1.f / 192.f);
  float rs = rsqrtf(ss * (1.f / 192.f) - mu * mu + 1e-5f);
#pragma unroll
  for (int t = 0; t < 24; ++t) {
    int d = j + 8 * t;
    float yn = (v[t] - mu) * rs * og[d] + ob[d];
    float z = xz[l * 384 + 192 + d];
    Ys[d * 36 + m2] = yn * siluf(z);
  }
  int mg = tid & 7, cg = tid >> 3;
  float acc[4][3] = {};
  for (int kc = 0; kc < 3; ++kc) {
    __syncthreads();
    for (int qi = tid; qi < 96 * 16; qi += 256) {
      int c = qi / 16, q = qi % 16;
      const float4 wv = *(const float4*)&ow[c * 192 + kc * 64 + q * 4];
      Bs[(q * 4 + 0) * 100 + c] = wv.x;
      Bs[(q * 4 + 1) * 100 + c] = wv.y;
      Bs[(q * 4 + 2) * 100 + c] = wv.z;
      Bs[(q * 4 + 3) * 100 + c] = wv.w;
    }
    __syncthreads();
    for (int kk = 0; kk < 64; ++kk) {
      int K = kc * 64 + kk;
      float a0 = Ys[K * 36 + 4 * mg + 0], a1 = Ys[K * 36 + 4 * mg + 1];
      float a2 = Ys[K * 36 + 4 * mg + 2], a3 = Ys[K * 36 + 4 * mg + 3];
      float b0 = Bs[kk * 100 + 3 * cg + 0], b1 = Bs[kk * 100 + 3 * cg + 1];
      float b2 = Bs[kk * 100 + 3 * cg + 2];
      acc[0][0] += a0 * b0; acc[0][1] += a0 * b1; acc[0][2] += a0 * b2;
      acc[1][0] += a1 * b0; acc[1][1] += a1 * b1; acc[1][2] += a1 * b2;
      acc[2][0] += a2 * b0; acc[2][1] += a2 * b1; acc[2][2] += a2 * b2;
      acc[3][0] += a3 * b0; acc[3][1] += a3 * b1; acc[3][2] += a3 * b2;
    }
  }
#pragma unroll
  for (int i = 0; i < 4; ++i) {
    int ll = l0 + 4 * mg + i;
#pragma unroll
    for (int jj = 0; jj < 3; ++jj) {
      int c = 3 * cg + jj;
      xout[ll * 96 + c] = xsrc[ll * 96 + c] + xn[ll * 96 + c] + acc[i][jj];
    }
  }
}

// ============ F: final 3x3 conv, split-K partials + reduce ============
__global__ void resconv_part(const float* __restrict__ x, const float* __restrict__ w,
                             float* __restrict__ pbuf) {
  int tile = blockIdx.x;
  int cs = blockIdx.y;
  int th0 = (tile >> 3) * 8, tw0 = (tile & 7) * 8;
  int cbase = cs * 12;
  __shared__ float xs[12][10][10];
  int tid = threadIdx.x;
  for (int idx = tid; idx < 12 * 100; idx += 256) {
    int cc = idx % 12;
    int pos = idx / 12;
    int hh = th0 + pos / 10 - 1;
    int ww = tw0 + pos % 10 - 1;
    float v = 0.f;
    if (hh >= 0 && hh < 64 && ww >= 0 && ww < 64) v = x[(hh * 64 + ww) * 96 + cbase + cc];
    xs[cc][pos / 10][pos % 10] = v;
  }
  __syncthreads();
  int lane = tid & 63;
  int th = lane >> 3, tw = lane & 7;
  int c0g = __builtin_amdgcn_readfirstlane(tid >> 6);
  float acc[24] = {};
  for (int cc = 0; cc < 12; ++cc) {
    float xv[9];
#pragma unroll
    for (int r = 0; r < 3; ++r)
#pragma unroll
      for (int q = 0; q < 3; ++q) xv[r * 3 + q] = xs[cc][th + r][tw + q];
    const float* wp = w + (c0g * 24) * 864 + (cbase + cc) * 9;
#pragma unroll 4
    for (int j = 0; j < 24; ++j) {
#pragma unroll
      for (int t = 0; t < 9; ++t) acc[j] += xv[t] * wp[j * 864 + t];
    }
  }
  int l = (th0 + th) * 64 + tw0 + tw;
  float* pb = pbuf + cs * 393216 + l * 96 + c0g * 24;
#pragma unroll
  for (int j = 0; j < 24; ++j) pb[j] = acc[j];
}

__global__ void resconv_reduce(const float* __restrict__ pbuf, const float* __restrict__ b,
                               const float* __restrict__ shortcut, float* __restrict__ out) {
  int idx = blockIdx.x * 256 + threadIdx.x;
  int c0 = idx % 96;
  float s = shortcut[idx] + b[c0];
#pragma unroll
  for (int ss = 0; ss < 8; ++ss) s += pbuf[ss * 393216 + idx];
  out[idx] = s;
}

extern "C" void kernel_launch(void* const* d_in, const int* in_sizes, int n_in,
                              void* d_out, int out_size, void* d_ws, size_t ws_size,
                              hipStream_t stream) {
  const float* x_in     = (const float*)d_in[0];
  const float* norm1_g  = (const float*)d_in[3];
  const float* norm1_b  = (const float*)d_in[4];
  const float* vssn_g   = (const float*)d_in[5];
  const float* vssn_b   = (const float*)d_in[6];
  const float* in_proj  = (const float*)d_in[7];
  const float* conv_w   = (const float*)d_in[8];
  const float* conv_b   = (const float*)d_in[9];
  const float* x_proj   = (const float*)d_in[10];
  const float* dt_w     = (const float*)d_in[11];
  const float* dt_b     = (const float*)d_in[12];
  const float* A_logs   = (const float*)d_in[13];
  const float* Ds       = (const float*)d_in[14];
  const float* outn_g   = (const float*)d_in[15];
  const float* outn_b   = (const float*)d_in[16];
  const float* out_proj = (const float*)d_in[17];
  const float* rc_w     = (const float*)d_in[18];
  const float* rc_b     = (const float*)d_in[19];

  float* ws = (float*)d_ws;
  float* xn    = ws + O_XN;
  float* xz    = ws + O_XZ;
  float* xconv = ws + O_XCONV;
  float* xconvT= ws + O_XCONVT;
  float* delta = ws + O_DELTA;
  float* Bm    = ws + O_BM;
  float* Cm    = ws + O_CM;
  float* ysb   = ws + O_YS;
  float* xcur  = ws + O_XCUR;
  float* pbuf  = ws + O_DELTA;  // reuse (delta dead after layer-2 scan)

  const float* xsrc = x_in;
  for (int i = 0; i < 2; ++i) {
    fusedA_kernel<<<dim3(64, 2), 256, 0, stream>>>(xsrc,
        norm1_g + i * 96, norm1_b + i * 96, vssn_g + i * 96, vssn_b + i * 96,
        in_proj + i * 36864, xn, xz);
    dwconvT_kernel<<<dim3(4, 4, 6), 256, 0, stream>>>(xz, conv_w + i * 1728,
        conv_b + i * 192, xconv, xconvT);
    projdelta_kernel<<<dim3(64, 4), 256, 0, stream>>>(xconv, xconvT,
        x_proj + i * 29184, dt_w + i * 4608, dt_b + i * 768, delta, Bm, Cm);
    scan_fused<<<768, 256, 0, stream>>>(delta, Bm, Cm, xconv, xconvT,
        A_logs + i * 12288, Ds + i * 768, ysb);
    combine_out<<<128, 256, 0, stream>>>(ysb, xz, xn, xsrc,
        outn_g + i * 192, outn_b + i * 192, out_proj + i * 18432, xcur);
    xsrc = xcur;
  }
  resconv_part<<<dim3(64, 8), 256, 0, stream>>>(xcur, rc_w, pbuf);
  resconv_reduce<<<1536, 256, 0, stream>>>(pbuf, rc_b, x_in, (float*)d_out);
}

// Round 4
// 575.910 us; speedup vs baseline: 1.7430x; 1.2791x over previous
//
#include <hip/hip_runtime.h>
#include <math.h>

// Problem constants (B=1)
#define LTOK 4096   // H*W tokens
#define CCH  96     // C
#define DIN_ 192
#define KDIR 4
#define NST  16
#define KD_  768    // K*DIN

// ---------------- workspace layout (floats) ----------------
#define O_XN     0
#define O_XZ     786432      // 4096*384
#define O_XCONV  2359296     // 192*4096
#define O_XCONVT 3145728
#define O_DELTA  3932160     // 768*4096 (scan order); reused as resconv pbuf at end
#define O_BM     7077888     // 4*4096*16 (k,l,n)
#define O_CM     7340032
#define O_YS     9961472     // 4*192*4096 (k, d, scanpos)  [d-major rows]
#define O_XCUR   13107200
// total 13500416 floats = ~51.5 MB

__device__ __forceinline__ float siluf(float x) { return x / (1.f + __expf(-x)); }

// ============ A: LN1 + LN2 + in_proj GEMM ============
// grid (64, 6), block 256. Block: 64 tokens x 64 output cols. LN recomputed per by.
__global__ void fusedA_kernel(const float* __restrict__ x, const float* __restrict__ g1,
                              const float* __restrict__ b1, const float* __restrict__ g2,
                              const float* __restrict__ b2, const float* __restrict__ w,
                              float* __restrict__ xn, float* __restrict__ xz) {
  __shared__ float As[96 * 72];  // As[k*72 + m] : LN2 output, k-major
  __shared__ float Bs[96 * 68];  // Bs[k*68 + n]
  int tid = threadIdx.x;
  int l0 = blockIdx.x * 64;
  int j0 = blockIdx.y * 64;
  int m = tid >> 2, j = tid & 3;       // token m (0..63), quad lane j
  int l = l0 + m;
  float v[24];
  float s = 0.f, ss = 0.f;
#pragma unroll
  for (int t = 0; t < 24; ++t) {
    int k = j + 4 * t;
    float vv = x[l * 96 + k];
    v[t] = vv; s += vv; ss += vv * vv;
  }
  s += __shfl_xor(s, 1); ss += __shfl_xor(ss, 1);
  s += __shfl_xor(s, 2); ss += __shfl_xor(ss, 2);
  float m1 = s * (1.f / 96.f);
  float rs1 = rsqrtf(ss * (1.f / 96.f) - m1 * m1 + 1e-5f);
  float s2 = 0.f, ss2 = 0.f;
#pragma unroll
  for (int t = 0; t < 24; ++t) {
    int k = j + 4 * t;
    float nv = (v[t] - m1) * rs1 * g1[k] + b1[k];
    v[t] = nv; s2 += nv; ss2 += nv * nv;
    if (blockIdx.y == 0) xn[l * 96 + k] = nv;
  }
  s2 += __shfl_xor(s2, 1); ss2 += __shfl_xor(ss2, 1);
  s2 += __shfl_xor(s2, 2); ss2 += __shfl_xor(ss2, 2);
  float m2 = s2 * (1.f / 96.f);
  float rs2 = rsqrtf(ss2 * (1.f / 96.f) - m2 * m2 + 1e-5f);
#pragma unroll
  for (int t = 0; t < 24; ++t) {
    int k = j + 4 * t;
    As[k * 72 + m] = (v[t] - m2) * rs2 * g2[k] + b2[k];
  }
  for (int qi = tid; qi < 64 * 24; qi += 256) {
    int nn = qi / 24, q = qi % 24;
    const float4 wv = *(const float4*)&w[(j0 + nn) * 96 + q * 4];
    Bs[(q * 4 + 0) * 68 + nn] = wv.x;
    Bs[(q * 4 + 1) * 68 + nn] = wv.y;
    Bs[(q * 4 + 2) * 68 + nn] = wv.z;
    Bs[(q * 4 + 3) * 68 + nn] = wv.w;
  }
  __syncthreads();
  int mg = tid & 15, ng = tid >> 4;
  float acc[4][4] = {};
  for (int k = 0; k < 96; ++k) {
    float a0 = As[k * 72 + 4 * mg + 0], a1 = As[k * 72 + 4 * mg + 1];
    float a2 = As[k * 72 + 4 * mg + 2], a3 = As[k * 72 + 4 * mg + 3];
    float b0 = Bs[k * 68 + 4 * ng + 0], b1_ = Bs[k * 68 + 4 * ng + 1];
    float b2_ = Bs[k * 68 + 4 * ng + 2], b3 = Bs[k * 68 + 4 * ng + 3];
    acc[0][0] += a0 * b0; acc[0][1] += a0 * b1_; acc[0][2] += a0 * b2_; acc[0][3] += a0 * b3;
    acc[1][0] += a1 * b0; acc[1][1] += a1 * b1_; acc[1][2] += a1 * b2_; acc[1][3] += a1 * b3;
    acc[2][0] += a2 * b0; acc[2][1] += a2 * b1_; acc[2][2] += a2 * b2_; acc[2][3] += a2 * b3;
    acc[3][0] += a3 * b0; acc[3][1] += a3 * b1_; acc[3][2] += a3 * b2_; acc[3][3] += a3 * b3;
  }
#pragma unroll
  for (int i = 0; i < 4; ++i) {
    float4 o = make_float4(acc[i][0], acc[i][1], acc[i][2], acc[i][3]);
    *(float4*)&xz[(l0 + 4 * mg + i) * 384 + j0 + 4 * ng] = o;
  }
}

// ============ B: depthwise conv 3x3 + silu, writes xconv AND xconvT ============
// grid (4,4,12): w-tile, h-tile, d-tile(16). block 256 = 16h x 16w.
__global__ void dwconvT_kernel(const float* __restrict__ xz, const float* __restrict__ cw,
                               const float* __restrict__ cb, float* __restrict__ xconv,
                               float* __restrict__ xconvT) {
  int w0 = blockIdx.x * 16, h0 = blockIdx.y * 16, d0 = blockIdx.z * 16;
  __shared__ float xs[324 * 17];  // [pos(18x18)][dd]
  int tid = threadIdx.x;
  for (int idx = tid; idx < 324 * 16; idx += 256) {
    int dd = idx & 15;
    int p = idx >> 4;
    int ph = p / 18, pw = p - ph * 18;
    int hh = h0 + ph - 1, ww = w0 + pw - 1;
    float v = 0.f;
    if (hh >= 0 && hh < 64 && ww >= 0 && ww < 64) v = xz[(hh * 64 + ww) * 384 + d0 + dd];
    xs[p * 17 + dd] = v;
  }
  __syncthreads();
  int wi = tid & 15, hi = tid >> 4;
  for (int dd = 0; dd < 16; ++dd) {
    int d = d0 + dd;
    float acc = cb[d];
    const float* wgt = cw + d * 9;
#pragma unroll
    for (int r = 0; r < 3; ++r)
#pragma unroll
      for (int c = 0; c < 3; ++c)
        acc += xs[((hi + r) * 18 + wi + c) * 17 + dd] * wgt[r * 3 + c];
    float o = siluf(acc);
    xconv[d * LTOK + (h0 + hi) * 64 + w0 + wi] = o;
    xconvT[d * LTOK + (w0 + wi) * 64 + h0 + hi] = o;
  }
}

// ============ C: x_proj + dt proj + softplus ============
__global__ void projdelta_kernel(const float* __restrict__ xconv, const float* __restrict__ xconvT,
                                 const float* __restrict__ xpw, const float* __restrict__ dtw,
                                 const float* __restrict__ dtb, float* __restrict__ delta,
                                 float* __restrict__ Bm, float* __restrict__ Cm) {
  int chunk = blockIdx.x;
  int k = blockIdx.y;
  int l0 = chunk * 64;
  __shared__ float xsm[192 * 64];
  __shared__ float xdm[38 * 64];
  int tid = threadIdx.x;
  const float* ub = ((k & 1) ? xconvT : xconv);
  bool rev = (k >= 2);
  for (int idx = tid; idx < 192 * 64; idx += 256) {
    int i = idx & 63, d = idx >> 6;
    int l = l0 + i;
    xsm[idx] = ub[d * LTOK + (rev ? 4095 - l : l)];
  }
  __syncthreads();
  for (int o = tid; o < 38 * 64; o += 256) {
    int i = o & 63, c = o >> 6;
    const float* wr = xpw + (k * 38 + c) * 192;
    float acc = 0.f;
#pragma unroll 8
    for (int d = 0; d < 192; ++d) acc += wr[d] * xsm[d * 64 + i];
    xdm[o] = acc;
    if (c >= 6) {
      int l = l0 + i;
      if (c < 22) Bm[(k * LTOK + l) * NST + (c - 6)] = acc;
      else        Cm[(k * LTOK + l) * NST + (c - 22)] = acc;
    }
  }
  __syncthreads();
  for (int o = tid; o < 192 * 64; o += 256) {
    int i = o & 63, d = o >> 6;
    float acc = dtb[k * 192 + d];
    const float* wr = dtw + (k * 192 + d) * 6;
#pragma unroll
    for (int r = 0; r < 6; ++r) acc += xdm[r * 64 + i] * wr[r];
    float sp = (acc > 20.f) ? acc : log1pf(__expf(acc));
    delta[(k * 192 + d) * LTOK + l0 + i] = sp;
  }
}

// ============ D: full selective scan, one block per kd channel. ============
// 768 blocks x 512 threads (8 waves). thread: n = tid&15, cq = tid>>4 (0..31).
// Phase A: 2 chunks per slot, serial 64. Phase B: wave log-scan over 64 chunks.
// Phase C: replay, 16-lane n-reduce, write ys in [k][d][l] layout.
__global__ __launch_bounds__(512) void scan_fused(
    const float* __restrict__ delta, const float* __restrict__ Bm,
    const float* __restrict__ Cm, const float* __restrict__ xconv,
    const float* __restrict__ xconvT, const float* __restrict__ A_logs,
    const float* __restrict__ Ds, float* __restrict__ ys) {
  int kd = blockIdx.x;
  int k = kd / 192, d = kd - k * 192;
  int tid = threadIdx.x;
  int n = tid & 15, cq = tid >> 4;
  const float* ub = ((k & 1) ? xconvT : xconv) + d * LTOK;
  bool rev = (k >= 2);
  float A = -__expf(A_logs[kd * NST + n]);
  const float* dp = delta + kd * LTOK;
  const float* bp = Bm + (k * LTOK) * NST + n;
  const float* cp = Cm + (k * LTOK) * NST + n;
  __shared__ float Ps[16 * 65], Qs[16 * 65], H0s[16 * 65];  // [n][c] pad 65
  // phase A: per-chunk (prod a, local end state)
#pragma unroll
  for (int i = 0; i < 2; ++i) {
    int c = cq + 32 * i;
    int l0 = c * 64;
    float P = 1.f, q = 0.f;
    for (int t = 0; t < 64; ++t) {
      int l = l0 + t;
      float dlt = dp[l];
      float u = ub[rev ? 4095 - l : l];
      float a = __expf(dlt * A);
      q = a * q + dlt * bp[l * NST] * u;
      P *= a;
    }
    Ps[n * 65 + c] = P; Qs[n * 65 + c] = q;
  }
  __syncthreads();
  // phase B: wave-parallel exclusive scan over 64 chunks, per n. 8 waves x 2 rounds.
  {
    int wv = tid >> 6, lane = tid & 63;
#pragma unroll
    for (int r = 0; r < 2; ++r) {
      int nn = wv + 8 * r;
      float P = Ps[nn * 65 + lane];
      float S = Qs[nn * 65 + lane];
#pragma unroll
      for (int off = 1; off < 64; off <<= 1) {
        float pp = __shfl_up(P, off);
        float sp = __shfl_up(S, off);
        if (lane >= off) { S = sp * P + S; P = pp * P; }
      }
      float h0 = __shfl_up(S, 1);
      if (lane == 0) h0 = 0.f;
      H0s[nn * 65 + lane] = h0;
    }
  }
  __syncthreads();
  // phase C: replay with correct h0, emit y
  float Dv = Ds[kd];
  float* yk = ys + (k * DIN_ + d) * LTOK;
#pragma unroll
  for (int i = 0; i < 2; ++i) {
    int c = cq + 32 * i;
    int l0 = c * 64;
    float h = H0s[n * 65 + c];
    for (int t = 0; t < 64; ++t) {
      int l = l0 + t;
      float dlt = dp[l];
      float u = ub[rev ? 4095 - l : l];
      float a = __expf(dlt * A);
      h = a * h + dlt * bp[l * NST] * u;
      float p = h * cp[l * NST];
      p += __shfl_xor(p, 1);
      p += __shfl_xor(p, 2);
      p += __shfl_xor(p, 4);
      p += __shfl_xor(p, 8);
      if (n == 0) yk[l] = p + Dv * u;
    }
  }
}

// ============ E: dir-combine + LN + silu-gate + out_proj + residuals ============
// grid 128, block 256. Block: 32 tokens, all 96 outputs. ys layout [k][d][l].
__global__ void combine_out(const float* __restrict__ ys, const float* __restrict__ xz,
                            const float* __restrict__ xn, const float* __restrict__ xsrc,
                            const float* __restrict__ og, const float* __restrict__ ob,
                            const float* __restrict__ ow, float* __restrict__ xout) {
  __shared__ float Ys[192 * 36];  // [d][m] gated LN output, k-major
  __shared__ float Bs[64 * 100];  // [kk][c]
  int tid = threadIdx.x;
  int l0 = blockIdx.x * 32;
  int m2 = tid >> 3, j = tid & 7;
  int l = l0 + m2;
  int Tl = ((l & 63) << 6) | (l >> 6);
  int l2 = 4095 - l, l3 = 4095 - Tl;
  float v[24];
  float s = 0.f, ss = 0.f;
#pragma unroll
  for (int t = 0; t < 24; ++t) {
    int d = j + 8 * t;
    float vv = ys[(0 * DIN_ + d) * LTOK + l] + ys[(1 * DIN_ + d) * LTOK + Tl]
             + ys[(2 * DIN_ + d) * LTOK + l2] + ys[(3 * DIN_ + d) * LTOK + l3];
    v[t] = vv; s += vv; ss += vv * vv;
  }
  s += __shfl_xor(s, 1); ss += __shfl_xor(ss, 1);
  s += __shfl_xor(s, 2); ss += __shfl_xor(ss, 2);
  s += __shfl_xor(s, 4); ss += __shfl_xor(ss, 4);
  float mu = s * (1.f / 192.f);
  float rs = rsqrtf(ss * (1.f / 192.f) - mu * mu + 1e-5f);
#pragma unroll
  for (int t = 0; t < 24; ++t) {
    int d = j + 8 * t;
    float yn = (v[t] - mu) * rs * og[d] + ob[d];
    float z = xz[l * 384 + 192 + d];
    Ys[d * 36 + m2] = yn * siluf(z);
  }
  int mg = tid & 7, cg = tid >> 3;
  float acc[4][3] = {};
  for (int kc = 0; kc < 3; ++kc) {
    __syncthreads();
    for (int qi = tid; qi < 96 * 16; qi += 256) {
      int c = qi / 16, q = qi % 16;
      const float4 wv = *(const float4*)&ow[c * 192 + kc * 64 + q * 4];
      Bs[(q * 4 + 0) * 100 + c] = wv.x;
      Bs[(q * 4 + 1) * 100 + c] = wv.y;
      Bs[(q * 4 + 2) * 100 + c] = wv.z;
      Bs[(q * 4 + 3) * 100 + c] = wv.w;
    }
    __syncthreads();
    for (int kk = 0; kk < 64; ++kk) {
      int K = kc * 64 + kk;
      float a0 = Ys[K * 36 + 4 * mg + 0], a1 = Ys[K * 36 + 4 * mg + 1];
      float a2 = Ys[K * 36 + 4 * mg + 2], a3 = Ys[K * 36 + 4 * mg + 3];
      float b0 = Bs[kk * 100 + 3 * cg + 0], b1 = Bs[kk * 100 + 3 * cg + 1];
      float b2 = Bs[kk * 100 + 3 * cg + 2];
      acc[0][0] += a0 * b0; acc[0][1] += a0 * b1; acc[0][2] += a0 * b2;
      acc[1][0] += a1 * b0; acc[1][1] += a1 * b1; acc[1][2] += a1 * b2;
      acc[2][0] += a2 * b0; acc[2][1] += a2 * b1; acc[2][2] += a2 * b2;
      acc[3][0] += a3 * b0; acc[3][1] += a3 * b1; acc[3][2] += a3 * b2;
    }
  }
#pragma unroll
  for (int i = 0; i < 4; ++i) {
    int ll = l0 + 4 * mg + i;
#pragma unroll
    for (int jj = 0; jj < 3; ++jj) {
      int c = 3 * cg + jj;
      xout[ll * 96 + c] = xsrc[ll * 96 + c] + xn[ll * 96 + c] + acc[i][jj];
    }
  }
}

// ============ F: final 3x3 conv, split-K partials + reduce ============
__global__ void resconv_part(const float* __restrict__ x, const float* __restrict__ w,
                             float* __restrict__ pbuf) {
  int tile = blockIdx.x;
  int cs = blockIdx.y;
  int th0 = (tile >> 3) * 8, tw0 = (tile & 7) * 8;
  int cbase = cs * 12;
  __shared__ float xs[12][10][10];
  int tid = threadIdx.x;
  for (int idx = tid; idx < 12 * 100; idx += 256) {
    int cc = idx % 12;
    int pos = idx / 12;
    int hh = th0 + pos / 10 - 1;
    int ww = tw0 + pos % 10 - 1;
    float v = 0.f;
    if (hh >= 0 && hh < 64 && ww >= 0 && ww < 64) v = x[(hh * 64 + ww) * 96 + cbase + cc];
    xs[cc][pos / 10][pos % 10] = v;
  }
  __syncthreads();
  int lane = tid & 63;
  int th = lane >> 3, tw = lane & 7;
  int c0g = __builtin_amdgcn_readfirstlane(tid >> 6);
  float acc[24] = {};
  for (int cc = 0; cc < 12; ++cc) {
    float xv[9];
#pragma unroll
    for (int r = 0; r < 3; ++r)
#pragma unroll
      for (int q = 0; q < 3; ++q) xv[r * 3 + q] = xs[cc][th + r][tw + q];
    const float* wp = w + (c0g * 24) * 864 + (cbase + cc) * 9;
#pragma unroll 4
    for (int j = 0; j < 24; ++j) {
#pragma unroll
      for (int t = 0; t < 9; ++t) acc[j] += xv[t] * wp[j * 864 + t];
    }
  }
  int l = (th0 + th) * 64 + tw0 + tw;
  float* pb = pbuf + cs * 393216 + l * 96 + c0g * 24;
#pragma unroll
  for (int j = 0; j < 24; ++j) pb[j] = acc[j];
}

__global__ void resconv_reduce(const float* __restrict__ pbuf, const float* __restrict__ b,
                               const float* __restrict__ shortcut, float* __restrict__ out) {
  int idx = blockIdx.x * 256 + threadIdx.x;
  int c0 = idx % 96;
  float s = shortcut[idx] + b[c0];
#pragma unroll
  for (int ss = 0; ss < 8; ++ss) s += pbuf[ss * 393216 + idx];
  out[idx] = s;
}

extern "C" void kernel_launch(void* const* d_in, const int* in_sizes, int n_in,
                              void* d_out, int out_size, void* d_ws, size_t ws_size,
                              hipStream_t stream) {
  const float* x_in     = (const float*)d_in[0];
  const float* norm1_g  = (const float*)d_in[3];
  const float* norm1_b  = (const float*)d_in[4];
  const float* vssn_g   = (const float*)d_in[5];
  const float* vssn_b   = (const float*)d_in[6];
  const float* in_proj  = (const float*)d_in[7];
  const float* conv_w   = (const float*)d_in[8];
  const float* conv_b   = (const float*)d_in[9];
  const float* x_proj   = (const float*)d_in[10];
  const float* dt_w     = (const float*)d_in[11];
  const float* dt_b     = (const float*)d_in[12];
  const float* A_logs   = (const float*)d_in[13];
  const float* Ds       = (const float*)d_in[14];
  const float* outn_g   = (const float*)d_in[15];
  const float* outn_b   = (const float*)d_in[16];
  const float* out_proj = (const float*)d_in[17];
  const float* rc_w     = (const float*)d_in[18];
  const float* rc_b     = (const float*)d_in[19];

  float* ws = (float*)d_ws;
  float* xn    = ws + O_XN;
  float* xz    = ws + O_XZ;
  float* xconv = ws + O_XCONV;
  float* xconvT= ws + O_XCONVT;
  float* delta = ws + O_DELTA;
  float* Bm    = ws + O_BM;
  float* Cm    = ws + O_CM;
  float* ysb   = ws + O_YS;
  float* xcur  = ws + O_XCUR;
  float* pbuf  = ws + O_DELTA;  // reuse (delta dead after layer-2 scan)

  const float* xsrc = x_in;
  for (int i = 0; i < 2; ++i) {
    fusedA_kernel<<<dim3(64, 6), 256, 0, stream>>>(xsrc,
        norm1_g + i * 96, norm1_b + i * 96, vssn_g + i * 96, vssn_b + i * 96,
        in_proj + i * 36864, xn, xz);
    dwconvT_kernel<<<dim3(4, 4, 12), 256, 0, stream>>>(xz, conv_w + i * 1728,
        conv_b + i * 192, xconv, xconvT);
    projdelta_kernel<<<dim3(64, 4), 256, 0, stream>>>(xconv, xconvT,
        x_proj + i * 29184, dt_w + i * 4608, dt_b + i * 768, delta, Bm, Cm);
    scan_fused<<<768, 512, 0, stream>>>(delta, Bm, Cm, xconv, xconvT,
        A_logs + i * 12288, Ds + i * 768, ysb);
    combine_out<<<128, 256, 0, stream>>>(ysb, xz, xn, xsrc,
        outn_g + i * 192, outn_b + i * 192, out_proj + i * 18432, xcur);
    xsrc = xcur;
  }
  resconv_part<<<dim3(64, 8), 256, 0, stream>>>(xcur, rc_w, pbuf);
  resconv_reduce<<<1536, 256, 0, stream>>>(pbuf, rc_b, x_in, (float*)d_out);
}